// Round 2
// baseline (569.326 us; speedup 1.0000x reference)
//
#include <hip/hip_runtime.h>
#include <hip/hip_bf16.h>

#define HIDN 1024
#define NH   8
#define DH   128
#define BB   4
#define SS   2048

typedef __bf16 bf16;
typedef bf16 bf16x4 __attribute__((ext_vector_type(4)));
typedef bf16 bf16x8 __attribute__((ext_vector_type(8)));
typedef float f32x4 __attribute__((ext_vector_type(4)));

static __device__ inline f32x4 mfma16(bf16x8 a, bf16x8 b, f32x4 c) {
    return __builtin_amdgcn_mfma_f32_16x16x32_bf16(a, b, c, 0, 0, 0);
}

// ---------------- weight convert + transpose: W[k][n] f32 -> WT[n][k] bf16 ----
__global__ void wconv_kernel(const float* __restrict__ W, bf16* __restrict__ WT) {
    int nb = blockIdx.x * 64;   // n block
    int kb = blockIdx.y * 64;   // k block
    int t = threadIdx.x;
    __shared__ bf16 tile[64][72];
    {
        int r = t >> 2, cp = (t & 3) * 16;
        #pragma unroll
        for (int j = 0; j < 16; j += 4) {
            float4 val = *(const float4*)&W[(size_t)(kb + r) * HIDN + nb + cp + j];
            tile[r][cp + j + 0] = (bf16)val.x;
            tile[r][cp + j + 1] = (bf16)val.y;
            tile[r][cp + j + 2] = (bf16)val.z;
            tile[r][cp + j + 3] = (bf16)val.w;
        }
    }
    __syncthreads();
    {
        int n = t >> 2, kp = (t & 3) * 16;
        bf16 o[16];
        #pragma unroll
        for (int j = 0; j < 16; ++j) o[j] = tile[kp + j][n];
        #pragma unroll
        for (int j = 0; j < 2; ++j)
            *(bf16x8*)&WT[(size_t)(nb + n) * HIDN + kb + kp + j * 8] = *(bf16x8*)&o[j * 8];
    }
}

// ---------------- GEMM: C[M][1024] = A[M][1024] @ Bt[1024][1024]^T -------------
template <bool AF32, typename CT>
__global__ __launch_bounds__(256, 2)
void gemm_bt_kernel(const void* __restrict__ Ap, const bf16* __restrict__ Bt,
                    CT* __restrict__ C, float alpha) {
    __shared__ bf16 Asm[128][40];
    __shared__ bf16 Bsm[128][40];
    int bm = blockIdx.x * 128;
    int bn = blockIdx.y * 128;
    int t = threadIdx.x;
    int wave = t >> 6, lane = t & 63;
    int wr = wave >> 1, wc = wave & 1;
    int lr = lane & 15, lg = lane >> 4;
    f32x4 acc[4][4] = {};
    for (int k0 = 0; k0 < HIDN; k0 += 32) {
        if constexpr (AF32) {
            const float* A = (const float*)Ap;
            int r = t >> 3, c = (t & 7) * 4;
            #pragma unroll
            for (int rr = 0; rr < 128; rr += 32) {
                float4 val = *(const float4*)&A[(size_t)(bm + rr + r) * HIDN + k0 + c];
                bf16x4 o = {(bf16)val.x, (bf16)val.y, (bf16)val.z, (bf16)val.w};
                *(bf16x4*)&Asm[rr + r][c] = o;
            }
        } else {
            const bf16* A = (const bf16*)Ap;
            int r = t >> 2, c = (t & 3) * 8;
            #pragma unroll
            for (int rr = 0; rr < 128; rr += 64)
                *(bf16x8*)&Asm[rr + r][c] = *(const bf16x8*)&A[(size_t)(bm + rr + r) * HIDN + k0 + c];
        }
        {
            int r = t >> 2, c = (t & 3) * 8;
            #pragma unroll
            for (int rr = 0; rr < 128; rr += 64)
                *(bf16x8*)&Bsm[rr + r][c] = *(const bf16x8*)&Bt[(size_t)(bn + rr + r) * HIDN + k0 + c];
        }
        __syncthreads();
        bf16x8 af[4], bfr[4];
        #pragma unroll
        for (int mi = 0; mi < 4; ++mi) af[mi] = *(const bf16x8*)&Asm[wr * 64 + mi * 16 + lr][lg * 8];
        #pragma unroll
        for (int ni = 0; ni < 4; ++ni) bfr[ni] = *(const bf16x8*)&Bsm[wc * 64 + ni * 16 + lr][lg * 8];
        #pragma unroll
        for (int mi = 0; mi < 4; ++mi)
            #pragma unroll
            for (int ni = 0; ni < 4; ++ni)
                acc[mi][ni] = mfma16(af[mi], bfr[ni], acc[mi][ni]);
        __syncthreads();
    }
    #pragma unroll
    for (int mi = 0; mi < 4; ++mi)
        #pragma unroll
        for (int ni = 0; ni < 4; ++ni)
            #pragma unroll
            for (int r = 0; r < 4; ++r) {
                int row = bm + wr * 64 + mi * 16 + lg * 4 + r;
                int col = bn + wc * 64 + ni * 16 + lr;
                C[(size_t)row * HIDN + col] = (CT)(acc[mi][ni][r] * alpha);
            }
}

// ---------------- vv [B,S,H*D] -> vvT [B*H, D, S] ------------------------------
__global__ void vt_kernel(const bf16* __restrict__ vv, bf16* __restrict__ vvT) {
    int st = blockIdx.x;   // S/64
    int bh = blockIdx.y;   // B*H
    int b = bh >> 3, h = bh & 7;
    int t = threadIdx.x;
    __shared__ bf16 tile[64][136];
    {
        int r = t >> 2, part = (t & 3) * 32;
        #pragma unroll
        for (int j = 0; j < 4; ++j)
            *(bf16x8*)&tile[r][part + j * 8] =
                *(const bf16x8*)&vv[((size_t)b * SS + st * 64 + r) * HIDN + h * DH + part + j * 8];
    }
    __syncthreads();
    {
        int d = t >> 1, kh = (t & 1) * 32;
        bf16 o[32];
        #pragma unroll
        for (int j = 0; j < 32; ++j) o[j] = tile[kh + j][d];
        #pragma unroll
        for (int j = 0; j < 4; ++j)
            *(bf16x8*)&vvT[((size_t)bh * DH + d) * SS + st * 64 + kh + j * 8] = *(bf16x8*)&o[j * 8];
    }
}

// ---------------- pass 1: softmax stats (row max m, row sum l) -----------------
__global__ __launch_bounds__(256, 2)
void attn_stats_kernel(const bf16* __restrict__ qq, const bf16* __restrict__ kk,
                       const int* __restrict__ mask,
                       float* __restrict__ mrow, float* __restrict__ lrow) {
    int qt = blockIdx.x, bh = blockIdx.y;
    int b = bh >> 3, h = bh & 7;
    int t = threadIdx.x;
    int wave = t >> 6, lane = t & 63;
    int wr = wave >> 1, wc = wave & 1;
    int lr = lane & 15, lg = lane >> 4;

    __shared__ float sm[2][128], sl[2][128], runm[128], runl[128];
    if (t < 128) { runm[t] = -3.4e38f; runl[t] = 0.f; }

    const bf16* qbase = qq + (size_t)b * SS * HIDN + h * DH;
    const bf16* kbase = kk + (size_t)b * SS * HIDN + h * DH;
    const int* mbase = mask + b * SS;

    bf16x8 qf[4][4];
    #pragma unroll
    for (int mi = 0; mi < 4; ++mi)
        #pragma unroll
        for (int kd = 0; kd < 4; ++kd)
            qf[mi][kd] = *(const bf16x8*)&qbase[(size_t)(qt * 128 + wr * 64 + mi * 16 + lr) * HIDN + kd * 32 + lg * 8];
    __syncthreads();

    for (int kt = 0; kt < SS / 128; ++kt) {
        f32x4 acc[4][4] = {};
        #pragma unroll
        for (int kd = 0; kd < 4; ++kd) {
            bf16x8 kf[4];
            #pragma unroll
            for (int ni = 0; ni < 4; ++ni)
                kf[ni] = *(const bf16x8*)&kbase[(size_t)(kt * 128 + wc * 64 + ni * 16 + lr) * HIDN + kd * 32 + lg * 8];
            #pragma unroll
            for (int mi = 0; mi < 4; ++mi)
                #pragma unroll
                for (int ni = 0; ni < 4; ++ni)
                    acc[mi][ni] = mfma16(qf[mi][kd], kf[ni], acc[mi][ni]);
        }
        bool mk[4];
        #pragma unroll
        for (int ni = 0; ni < 4; ++ni)
            mk[ni] = mbase[kt * 128 + wc * 64 + ni * 16 + lr] != 0;

        float tm[16], tl[16];
        #pragma unroll
        for (int mi = 0; mi < 4; ++mi)
            #pragma unroll
            for (int r = 0; r < 4; ++r) {
                float v0 = mk[0] ? -1e9f : acc[mi][0][r];
                float v1 = mk[1] ? -1e9f : acc[mi][1][r];
                float v2 = mk[2] ? -1e9f : acc[mi][2][r];
                float v3 = mk[3] ? -1e9f : acc[mi][3][r];
                float mx = fmaxf(fmaxf(v0, v1), fmaxf(v2, v3));
                #pragma unroll
                for (int o = 1; o < 16; o <<= 1) mx = fmaxf(mx, __shfl_xor(mx, o));
                float se = __expf(v0 - mx) + __expf(v1 - mx) + __expf(v2 - mx) + __expf(v3 - mx);
                #pragma unroll
                for (int o = 1; o < 16; o <<= 1) se += __shfl_xor(se, o);
                tm[mi * 4 + r] = mx;
                tl[mi * 4 + r] = se;
            }
        if (lr == 0) {
            #pragma unroll
            for (int mi = 0; mi < 4; ++mi)
                #pragma unroll
                for (int r = 0; r < 4; ++r) {
                    int row = wr * 64 + mi * 16 + lg * 4 + r;
                    sm[wc][row] = tm[mi * 4 + r];
                    sl[wc][row] = tl[mi * 4 + r];
                }
        }
        __syncthreads();
        if (t < 128) {
            float m0 = sm[0][t], m1 = sm[1][t];
            float mt = fmaxf(m0, m1);
            float lt = sl[0][t] * __expf(m0 - mt) + sl[1][t] * __expf(m1 - mt);
            float mo = runm[t];
            float mn = fmaxf(mo, mt);
            runl[t] = runl[t] * __expf(mo - mn) + lt * __expf(mt - mn);
            runm[t] = mn;
        }
        __syncthreads();
    }
    if (t < 128) {
        size_t idx = (size_t)bh * SS + qt * 128 + t;
        mrow[idx] = runm[t];
        lrow[idx] = 1.0f / runl[t];
    }
}

// ---------------- pass 2: probs (-> f32 attn out + LDS bf16) and ctx = P @ V ---
__global__ __launch_bounds__(256, 1)
void attn_pv_kernel(const bf16* __restrict__ qq, const bf16* __restrict__ kk,
                    const bf16* __restrict__ vvT, const int* __restrict__ mask,
                    const float* __restrict__ mrow, const float* __restrict__ lrow,
                    float* __restrict__ attn, bf16* __restrict__ ctx) {
    int qt = blockIdx.x, bh = blockIdx.y;
    int b = bh >> 3, h = bh & 7;
    int t = threadIdx.x;
    int wave = t >> 6, lane = t & 63;
    int wr = wave >> 1, wc = wave & 1;
    int lr = lane & 15, lg = lane >> 4;

    __shared__ bf16 P[128][136];

    const bf16* qbase = qq + (size_t)b * SS * HIDN + h * DH;
    const bf16* kbase = kk + (size_t)b * SS * HIDN + h * DH;
    const int* mbase = mask + b * SS;

    bf16x8 qf[4][4];
    #pragma unroll
    for (int mi = 0; mi < 4; ++mi)
        #pragma unroll
        for (int kd = 0; kd < 4; ++kd)
            qf[mi][kd] = *(const bf16x8*)&qbase[(size_t)(qt * 128 + wr * 64 + mi * 16 + lr) * HIDN + kd * 32 + lg * 8];

    float rm[16], rl[16];
    #pragma unroll
    for (int mi = 0; mi < 4; ++mi)
        #pragma unroll
        for (int r = 0; r < 4; ++r) {
            size_t idx = (size_t)bh * SS + qt * 128 + wr * 64 + mi * 16 + lg * 4 + r;
            rm[mi * 4 + r] = mrow[idx];
            rl[mi * 4 + r] = lrow[idx];
        }

    f32x4 cacc[4][4] = {};
    for (int kt = 0; kt < SS / 128; ++kt) {
        f32x4 acc[4][4] = {};
        #pragma unroll
        for (int kd = 0; kd < 4; ++kd) {
            bf16x8 kf[4];
            #pragma unroll
            for (int ni = 0; ni < 4; ++ni)
                kf[ni] = *(const bf16x8*)&kbase[(size_t)(kt * 128 + wc * 64 + ni * 16 + lr) * HIDN + kd * 32 + lg * 8];
            #pragma unroll
            for (int mi = 0; mi < 4; ++mi)
                #pragma unroll
                for (int ni = 0; ni < 4; ++ni)
                    acc[mi][ni] = mfma16(qf[mi][kd], kf[ni], acc[mi][ni]);
        }
        bool mk[4];
        #pragma unroll
        for (int ni = 0; ni < 4; ++ni)
            mk[ni] = mbase[kt * 128 + wc * 64 + ni * 16 + lr] != 0;

        #pragma unroll
        for (int mi = 0; mi < 4; ++mi)
            #pragma unroll
            for (int ni = 0; ni < 4; ++ni)
                #pragma unroll
                for (int r = 0; r < 4; ++r) {
                    float s = mk[ni] ? -1e9f : acc[mi][ni][r];
                    float p = __expf(s - rm[mi * 4 + r]) * rl[mi * 4 + r];
                    int rowl = wr * 64 + mi * 16 + lg * 4 + r;
                    int coll = wc * 64 + ni * 16 + lr;
                    P[rowl][coll] = (bf16)p;
                    attn[((size_t)bh * SS + qt * 128 + rowl) * SS + kt * 128 + coll] = p;
                }
        __syncthreads();
        #pragma unroll
        for (int ks = 0; ks < 4; ++ks) {
            bf16x8 pf[4], vf[4];
            #pragma unroll
            for (int mi = 0; mi < 4; ++mi)
                pf[mi] = *(const bf16x8*)&P[wr * 64 + mi * 16 + lr][ks * 32 + lg * 8];
            #pragma unroll
            for (int ni = 0; ni < 4; ++ni)
                vf[ni] = *(const bf16x8*)&vvT[((size_t)bh * DH + wc * 64 + ni * 16 + lr) * SS + kt * 128 + ks * 32 + lg * 8];
            #pragma unroll
            for (int mi = 0; mi < 4; ++mi)
                #pragma unroll
                for (int ni = 0; ni < 4; ++ni)
                    cacc[mi][ni] = mfma16(pf[mi], vf[ni], cacc[mi][ni]);
        }
        __syncthreads();
    }
    #pragma unroll
    for (int mi = 0; mi < 4; ++mi)
        #pragma unroll
        for (int ni = 0; ni < 4; ++ni)
            #pragma unroll
            for (int r = 0; r < 4; ++r) {
                int qrow = qt * 128 + wr * 64 + mi * 16 + lg * 4 + r;
                int d = wc * 64 + ni * 16 + lr;
                ctx[((size_t)b * SS + qrow) * HIDN + h * DH + d] = (bf16)cacc[mi][ni][r];
            }
}

extern "C" void kernel_launch(void* const* d_in, const int* in_sizes, int n_in,
                              void* d_out, int out_size, void* d_ws, size_t ws_size,
                              hipStream_t stream) {
    const float* q = (const float*)d_in[0];
    const float* k = (const float*)d_in[1];
    const float* v = (const float*)d_in[2];
    const int* mask = (const int*)d_in[3];
    const float* Wq = (const float*)d_in[4];
    const float* Wk = (const float*)d_in[5];
    const float* Wv = (const float*)d_in[6];
    const float* Wo = (const float*)d_in[7];
    (void)in_sizes; (void)n_in; (void)out_size; (void)ws_size;

    float* outp = (float*)d_out;                       // out [B,S,HID], f32
    float* attn = outp + (size_t)BB * SS * HIDN;       // attn [B,H,S,S], f32

    char* ws = (char*)d_ws;
    size_t off = 0;
    auto alloc = [&](size_t bytes) { char* p = ws + off; off += (bytes + 255) & ~(size_t)255; return p; };
    const size_t wbytes = (size_t)HIDN * HIDN * sizeof(bf16);
    const size_t tbytes = (size_t)BB * SS * HIDN * sizeof(bf16);
    bf16* WqT = (bf16*)alloc(wbytes);
    bf16* WkT = (bf16*)alloc(wbytes);
    bf16* WvT = (bf16*)alloc(wbytes);
    bf16* WoT = (bf16*)alloc(wbytes);
    bf16* qqb = (bf16*)alloc(tbytes);
    bf16* kkb = (bf16*)alloc(tbytes);
    bf16* vvb = (bf16*)alloc(tbytes);
    bf16* vvTb = (bf16*)alloc(tbytes);
    bf16* ctxb = (bf16*)alloc(tbytes);
    float* mrowb = (float*)alloc((size_t)BB * NH * SS * sizeof(float));
    float* lrowb = (float*)alloc((size_t)BB * NH * SS * sizeof(float));

    dim3 blk(256);
    wconv_kernel<<<dim3(16, 16), blk, 0, stream>>>(Wq, WqT);
    wconv_kernel<<<dim3(16, 16), blk, 0, stream>>>(Wk, WkT);
    wconv_kernel<<<dim3(16, 16), blk, 0, stream>>>(Wv, WvT);
    wconv_kernel<<<dim3(16, 16), blk, 0, stream>>>(Wo, WoT);

    const float scale = 0.08838834764831845f;  // 1/sqrt(128)
    gemm_bt_kernel<true, bf16><<<dim3(64, 8), blk, 0, stream>>>(q, WqT, qqb, scale);
    gemm_bt_kernel<true, bf16><<<dim3(64, 8), blk, 0, stream>>>(k, WkT, kkb, 1.0f);
    gemm_bt_kernel<true, bf16><<<dim3(64, 8), blk, 0, stream>>>(v, WvT, vvb, 1.0f);

    vt_kernel<<<dim3(SS / 64, BB * NH), blk, 0, stream>>>(vvb, vvTb);

    attn_stats_kernel<<<dim3(SS / 128, BB * NH), blk, 0, stream>>>(qqb, kkb, mask, mrowb, lrowb);
    attn_pv_kernel<<<dim3(SS / 128, BB * NH), blk, 0, stream>>>(qqb, kkb, vvTb, mask, mrowb, lrowb, attn, ctxb);

    gemm_bt_kernel<false, float><<<dim3(64, 8), blk, 0, stream>>>(ctxb, WoT, outp, 1.0f);
}

// Round 3
// 404.593 us; speedup vs baseline: 1.4072x; 1.4072x over previous
//
#include <hip/hip_runtime.h>
#include <hip/hip_bf16.h>

#define HIDN 1024
#define NH   8
#define DH   128
#define BB   4
#define SS   2048

typedef __bf16 bf16;
typedef bf16 bf16x4 __attribute__((ext_vector_type(4)));
typedef bf16 bf16x8 __attribute__((ext_vector_type(8)));
typedef float f32x4 __attribute__((ext_vector_type(4)));

static __device__ inline f32x4 mfma16(bf16x8 a, bf16x8 b, f32x4 c) {
    return __builtin_amdgcn_mfma_f32_16x16x32_bf16(a, b, c, 0, 0, 0);
}

// async global->LDS, 16B per lane. lds ptr must be wave-uniform; g is per-lane.
static __device__ inline void gload_lds16(const void* g, void* l) {
    __builtin_amdgcn_global_load_lds(
        (const __attribute__((address_space(1))) unsigned int*)g,
        (__attribute__((address_space(3))) unsigned int*)l, 16, 0, 0);
}

// ---------------- q,k,v f32 -> bf16 (vectorized) -------------------------------
__global__ void cvt_kernel(const float* __restrict__ q, const float* __restrict__ k,
                           const float* __restrict__ v,
                           bf16* __restrict__ qo, bf16* __restrict__ ko, bf16* __restrict__ vo) {
    const float* src = blockIdx.y == 0 ? q : blockIdx.y == 1 ? k : v;
    bf16* dst = blockIdx.y == 0 ? qo : blockIdx.y == 1 ? ko : vo;
    const size_t n = (size_t)BB * SS * HIDN;
    for (size_t i = ((size_t)blockIdx.x * blockDim.x + threadIdx.x) * 8; i < n;
         i += (size_t)gridDim.x * blockDim.x * 8) {
        float4 a = *(const float4*)&src[i];
        float4 b = *(const float4*)&src[i + 4];
        bf16x8 o = {(bf16)a.x, (bf16)a.y, (bf16)a.z, (bf16)a.w,
                    (bf16)b.x, (bf16)b.y, (bf16)b.z, (bf16)b.w};
        *(bf16x8*)&dst[i] = o;
    }
}

// ---------------- weight convert + transpose: W[k][n] f32 -> WT[n][k] bf16 -----
__global__ void wconv_kernel(const float* __restrict__ W0, const float* __restrict__ W1,
                             const float* __restrict__ W2, const float* __restrict__ W3,
                             bf16* __restrict__ O) {
    const float* W = blockIdx.z == 0 ? W0 : blockIdx.z == 1 ? W1 : blockIdx.z == 2 ? W2 : W3;
    bf16* WT = O + (size_t)blockIdx.z * HIDN * HIDN;
    int nb = blockIdx.x * 64;
    int kb = blockIdx.y * 64;
    int t = threadIdx.x;
    __shared__ bf16 tile[64][72];
    {
        int r = t >> 2, cp = (t & 3) * 16;
        #pragma unroll
        for (int j = 0; j < 16; j += 4) {
            float4 val = *(const float4*)&W[(size_t)(kb + r) * HIDN + nb + cp + j];
            tile[r][cp + j + 0] = (bf16)val.x;
            tile[r][cp + j + 1] = (bf16)val.y;
            tile[r][cp + j + 2] = (bf16)val.z;
            tile[r][cp + j + 3] = (bf16)val.w;
        }
    }
    __syncthreads();
    {
        int n = t >> 2, kp = (t & 3) * 16;
        bf16 o[16];
        #pragma unroll
        for (int j = 0; j < 16; ++j) o[j] = tile[kp + j][n];
        #pragma unroll
        for (int j = 0; j < 2; ++j)
            *(bf16x8*)&WT[(size_t)(nb + n) * HIDN + kb + kp + j * 8] = *(bf16x8*)&o[j * 8];
    }
}

// ---------------- GEMM: C[M][1024] = A[M][1024] @ Bt[1024][1024]^T -------------
// m97 structure: BK=64, global_load_lds 16B, XOR-swizzled LDS (linear dest +
// pre-swizzled source + swizzled read), 128x128 tile, XCD-swizzled grid.
template <typename CT>
__global__ __launch_bounds__(256, 2)
void gemm_bt_kernel(const bf16* __restrict__ A, const bf16* __restrict__ Bt,
                    CT* __restrict__ C, float alpha) {
    __shared__ bf16 Asm[128 * 64];
    __shared__ bf16 Bsm[128 * 64];
    int orig = blockIdx.x + blockIdx.y * gridDim.x;  // 512 wgs, x fastest
    int virt = (orig & 7) * 64 + (orig >> 3);        // XCD x -> one N-band
    int bm = (virt & 63) * 128;
    int bn = (virt >> 6) * 128;
    int t = threadIdx.x;
    int wave = t >> 6, lane = t & 63;
    int wr = wave >> 1, wc = wave & 1;
    int lr = lane & 15, lg = lane >> 4;
    f32x4 acc[4][4] = {};
    for (int k0 = 0; k0 < HIDN; k0 += 64) {
        #pragma unroll
        for (int i = 0; i < 4; ++i) {
            int o = i * 4096 + wave * 1024 + lane * 16;  // lds byte offset
            int r = o >> 7, cb = o & 127;
            int cbs = cb ^ ((r & 7) << 4);               // inverse-swizzled source
            gload_lds16(&A[(size_t)(bm + r) * HIDN + k0 + (cbs >> 1)],
                        (char*)Asm + i * 4096 + wave * 1024);
            gload_lds16(&Bt[(size_t)(bn + r) * HIDN + k0 + (cbs >> 1)],
                        (char*)Bsm + i * 4096 + wave * 1024);
        }
        asm volatile("s_waitcnt vmcnt(0)" ::: "memory");
        __syncthreads();
        #pragma unroll
        for (int kd = 0; kd < 2; ++kd) {
            bf16x8 af[4], bfr[4];
            #pragma unroll
            for (int mi = 0; mi < 4; ++mi) {
                int row = wr * 64 + mi * 16 + lr;
                int cb = (kd * 64 + lg * 16) ^ ((row & 7) << 4);
                af[mi] = *(const bf16x8*)((const char*)Asm + row * 128 + cb);
            }
            #pragma unroll
            for (int ni = 0; ni < 4; ++ni) {
                int row = wc * 64 + ni * 16 + lr;
                int cb = (kd * 64 + lg * 16) ^ ((row & 7) << 4);
                bfr[ni] = *(const bf16x8*)((const char*)Bsm + row * 128 + cb);
            }
            #pragma unroll
            for (int mi = 0; mi < 4; ++mi)
                #pragma unroll
                for (int ni = 0; ni < 4; ++ni)
                    acc[mi][ni] = mfma16(af[mi], bfr[ni], acc[mi][ni]);
        }
        __syncthreads();
    }
    #pragma unroll
    for (int mi = 0; mi < 4; ++mi)
        #pragma unroll
        for (int ni = 0; ni < 4; ++ni)
            #pragma unroll
            for (int r = 0; r < 4; ++r) {
                int row = bm + wr * 64 + mi * 16 + lg * 4 + r;
                int col = bn + wc * 64 + ni * 16 + lr;
                C[(size_t)row * HIDN + col] = (CT)(acc[mi][ni][r] * alpha);
            }
}

// ---------------- vv [B,S,H*D] -> vvT [B*H, D, S] ------------------------------
__global__ void vt_kernel(const bf16* __restrict__ vv, bf16* __restrict__ vvT) {
    int st = blockIdx.x;   // S/64
    int bh = blockIdx.y;   // B*H
    int b = bh >> 3, h = bh & 7;
    int t = threadIdx.x;
    __shared__ bf16 tile[64][136];
    {
        int r = t >> 2, part = (t & 3) * 32;
        #pragma unroll
        for (int j = 0; j < 4; ++j)
            *(bf16x8*)&tile[r][part + j * 8] =
                *(const bf16x8*)&vv[((size_t)b * SS + st * 64 + r) * HIDN + h * DH + part + j * 8];
    }
    __syncthreads();
    {
        int d = t >> 1, kh = (t & 1) * 32;
        bf16 o[32];
        #pragma unroll
        for (int j = 0; j < 32; ++j) o[j] = tile[kh + j][d];
        #pragma unroll
        for (int j = 0; j < 4; ++j)
            *(bf16x8*)&vvT[((size_t)bh * DH + d) * SS + st * 64 + kh + j * 8] = *(bf16x8*)&o[j * 8];
    }
}

// K-tile staging into swizzled LDS (32KB, 128 rows x 256B), shared by both passes
static __device__ inline void stage_k(const bf16* kbase, int kt, bf16* Ksm, int wave, int lane) {
    #pragma unroll
    for (int i = 0; i < 8; ++i) {
        int o = i * 4096 + wave * 1024 + lane * 16;
        int r = o >> 8, cb = o & 255;
        int cbs = cb ^ ((r & 7) << 4);
        gload_lds16(&kbase[(size_t)(kt * 128 + r) * HIDN + (cbs >> 1)],
                    (char*)Ksm + i * 4096 + wave * 1024);
    }
    asm volatile("s_waitcnt vmcnt(0)" ::: "memory");
}

static __device__ inline bf16x8 read_k(const bf16* Ksm, int row, int cstart_bytes) {
    int cb = cstart_bytes ^ ((row & 7) << 4);
    return *(const bf16x8*)((const char*)Ksm + row * 256 + cb);
}

// ---------------- pass 1: softmax stats (row max m, row inv-sum) ---------------
__global__ __launch_bounds__(256, 2)
void attn_stats_kernel(const bf16* __restrict__ qq, const bf16* __restrict__ kk,
                       const int* __restrict__ mask,
                       float* __restrict__ mrow, float* __restrict__ lrow) {
    int orig = blockIdx.x + blockIdx.y * gridDim.x;  // 512
    int virt = (orig & 7) * 64 + (orig >> 3);        // 4 bh-groups per XCD
    int qt = virt & 15, bh = virt >> 4;
    int b = bh >> 3, h = bh & 7;
    int t = threadIdx.x;
    int wave = t >> 6, lane = t & 63;
    int wr = wave >> 1, wc = wave & 1;
    int lr = lane & 15, lg = lane >> 4;

    __shared__ bf16 Ksm[128 * 128];
    __shared__ float sm[2][128], sl[2][128], runm[128], runl[128];
    if (t < 128) { runm[t] = -3.4e38f; runl[t] = 0.f; }

    const bf16* qbase = qq + (size_t)b * SS * HIDN + h * DH;
    const bf16* kbase = kk + (size_t)b * SS * HIDN + h * DH;
    const int* mbase = mask + b * SS;

    bf16x8 qf[4][4];
    #pragma unroll
    for (int mi = 0; mi < 4; ++mi)
        #pragma unroll
        for (int kd = 0; kd < 4; ++kd)
            qf[mi][kd] = *(const bf16x8*)&qbase[(size_t)(qt * 128 + wr * 64 + mi * 16 + lr) * HIDN + kd * 32 + lg * 8];

    for (int kt = 0; kt < SS / 128; ++kt) {
        stage_k(kbase, kt, Ksm, wave, lane);
        __syncthreads();
        f32x4 acc[4][4] = {};
        #pragma unroll
        for (int kd = 0; kd < 4; ++kd) {
            bf16x8 kf[4];
            #pragma unroll
            for (int ni = 0; ni < 4; ++ni)
                kf[ni] = read_k(Ksm, wc * 64 + ni * 16 + lr, kd * 64 + lg * 16);
            #pragma unroll
            for (int mi = 0; mi < 4; ++mi)
                #pragma unroll
                for (int ni = 0; ni < 4; ++ni)
                    acc[mi][ni] = mfma16(qf[mi][kd], kf[ni], acc[mi][ni]);
        }
        bool mk[4];
        #pragma unroll
        for (int ni = 0; ni < 4; ++ni)
            mk[ni] = mbase[kt * 128 + wc * 64 + ni * 16 + lr] != 0;

        float tm[16], tl[16];
        #pragma unroll
        for (int mi = 0; mi < 4; ++mi)
            #pragma unroll
            for (int r = 0; r < 4; ++r) {
                float v0 = mk[0] ? -1e9f : acc[mi][0][r];
                float v1 = mk[1] ? -1e9f : acc[mi][1][r];
                float v2 = mk[2] ? -1e9f : acc[mi][2][r];
                float v3 = mk[3] ? -1e9f : acc[mi][3][r];
                float mx = fmaxf(fmaxf(v0, v1), fmaxf(v2, v3));
                #pragma unroll
                for (int o = 1; o < 16; o <<= 1) mx = fmaxf(mx, __shfl_xor(mx, o));
                float se = __expf(v0 - mx) + __expf(v1 - mx) + __expf(v2 - mx) + __expf(v3 - mx);
                #pragma unroll
                for (int o = 1; o < 16; o <<= 1) se += __shfl_xor(se, o);
                tm[mi * 4 + r] = mx;
                tl[mi * 4 + r] = se;
            }
        if (lr == 0) {
            #pragma unroll
            for (int mi = 0; mi < 4; ++mi)
                #pragma unroll
                for (int r = 0; r < 4; ++r) {
                    int row = wr * 64 + mi * 16 + lg * 4 + r;
                    sm[wc][row] = tm[mi * 4 + r];
                    sl[wc][row] = tl[mi * 4 + r];
                }
        }
        __syncthreads();
        if (t < 128) {
            float m0 = sm[0][t], m1 = sm[1][t];
            float mt = fmaxf(m0, m1);
            float lt = sl[0][t] * __expf(m0 - mt) + sl[1][t] * __expf(m1 - mt);
            float mo = runm[t];
            float mn = fmaxf(mo, mt);
            runl[t] = runl[t] * __expf(mo - mn) + lt * __expf(mt - mn);
            runm[t] = mn;
        }
    }
    __syncthreads();
    if (t < 128) {
        size_t idx = (size_t)bh * SS + qt * 128 + t;
        mrow[idx] = runm[t];
        lrow[idx] = 1.0f / runl[t];
    }
}

// ---------------- pass 2: probs (-> f32 attn out + LDS bf16) and ctx = P @ V ---
__global__ __launch_bounds__(256, 2)
void attn_pv_kernel(const bf16* __restrict__ qq, const bf16* __restrict__ kk,
                    const bf16* __restrict__ vvT, const int* __restrict__ mask,
                    const float* __restrict__ mrow, const float* __restrict__ lrow,
                    float* __restrict__ attn, bf16* __restrict__ ctx) {
    int orig = blockIdx.x + blockIdx.y * gridDim.x;
    int virt = (orig & 7) * 64 + (orig >> 3);
    int qt = virt & 15, bh = virt >> 4;
    int b = bh >> 3, h = bh & 7;
    int t = threadIdx.x;
    int wave = t >> 6, lane = t & 63;
    int wr = wave >> 1, wc = wave & 1;
    int lr = lane & 15, lg = lane >> 4;

    __shared__ bf16 Ksm[128 * 128];
    __shared__ bf16 P[128][136];

    const bf16* qbase = qq + (size_t)b * SS * HIDN + h * DH;
    const bf16* kbase = kk + (size_t)b * SS * HIDN + h * DH;
    const int* mbase = mask + b * SS;

    bf16x8 qf[4][4];
    #pragma unroll
    for (int mi = 0; mi < 4; ++mi)
        #pragma unroll
        for (int kd = 0; kd < 4; ++kd)
            qf[mi][kd] = *(const bf16x8*)&qbase[(size_t)(qt * 128 + wr * 64 + mi * 16 + lr) * HIDN + kd * 32 + lg * 8];

    float rm[16], rl[16];
    #pragma unroll
    for (int mi = 0; mi < 4; ++mi)
        #pragma unroll
        for (int r = 0; r < 4; ++r) {
            size_t idx = (size_t)bh * SS + qt * 128 + wr * 64 + mi * 16 + lg * 4 + r;
            rm[mi * 4 + r] = mrow[idx];
            rl[mi * 4 + r] = lrow[idx];
        }

    f32x4 cacc[4][4] = {};
    for (int kt = 0; kt < SS / 128; ++kt) {
        stage_k(kbase, kt, Ksm, wave, lane);
        __syncthreads();
        f32x4 acc[4][4] = {};
        #pragma unroll
        for (int kd = 0; kd < 4; ++kd) {
            bf16x8 kf[4];
            #pragma unroll
            for (int ni = 0; ni < 4; ++ni)
                kf[ni] = read_k(Ksm, wc * 64 + ni * 16 + lr, kd * 64 + lg * 16);
            #pragma unroll
            for (int mi = 0; mi < 4; ++mi)
                #pragma unroll
                for (int ni = 0; ni < 4; ++ni)
                    acc[mi][ni] = mfma16(qf[mi][kd], kf[ni], acc[mi][ni]);
        }
        bool mk[4];
        #pragma unroll
        for (int ni = 0; ni < 4; ++ni)
            mk[ni] = mbase[kt * 128 + wc * 64 + ni * 16 + lr] != 0;

        #pragma unroll
        for (int mi = 0; mi < 4; ++mi)
            #pragma unroll
            for (int ni = 0; ni < 4; ++ni)
                #pragma unroll
                for (int r = 0; r < 4; ++r) {
                    float s = mk[ni] ? -1e9f : acc[mi][ni][r];
                    float p = __expf(s - rm[mi * 4 + r]) * rl[mi * 4 + r];
                    int rowl = wr * 64 + mi * 16 + lg * 4 + r;
                    int coll = wc * 64 + ni * 16 + lr;
                    P[rowl][coll] = (bf16)p;
                    __builtin_nontemporal_store(
                        p, &attn[((size_t)bh * SS + qt * 128 + rowl) * SS + kt * 128 + coll]);
                }
        __syncthreads();
        #pragma unroll
        for (int ks = 0; ks < 4; ++ks) {
            bf16x8 pf[4], vf[4];
            #pragma unroll
            for (int mi = 0; mi < 4; ++mi)
                pf[mi] = *(const bf16x8*)&P[wr * 64 + mi * 16 + lr][ks * 32 + lg * 8];
            #pragma unroll
            for (int ni = 0; ni < 4; ++ni)
                vf[ni] = *(const bf16x8*)&vvT[((size_t)bh * DH + wc * 64 + ni * 16 + lr) * SS + kt * 128 + ks * 32 + lg * 8];
            #pragma unroll
            for (int mi = 0; mi < 4; ++mi)
                #pragma unroll
                for (int ni = 0; ni < 4; ++ni)
                    cacc[mi][ni] = mfma16(pf[mi], vf[ni], cacc[mi][ni]);
        }
        __syncthreads();
    }
    #pragma unroll
    for (int mi = 0; mi < 4; ++mi)
        #pragma unroll
        for (int ni = 0; ni < 4; ++ni)
            #pragma unroll
            for (int r = 0; r < 4; ++r) {
                int qrow = qt * 128 + wr * 64 + mi * 16 + lg * 4 + r;
                int d = wc * 64 + ni * 16 + lr;
                ctx[((size_t)b * SS + qrow) * HIDN + h * DH + d] = (bf16)cacc[mi][ni][r];
            }
}

extern "C" void kernel_launch(void* const* d_in, const int* in_sizes, int n_in,
                              void* d_out, int out_size, void* d_ws, size_t ws_size,
                              hipStream_t stream) {
    const float* q = (const float*)d_in[0];
    const float* k = (const float*)d_in[1];
    const float* v = (const float*)d_in[2];
    const int* mask = (const int*)d_in[3];
    const float* Wq = (const float*)d_in[4];
    const float* Wk = (const float*)d_in[5];
    const float* Wv = (const float*)d_in[6];
    const float* Wo = (const float*)d_in[7];
    (void)in_sizes; (void)n_in; (void)out_size; (void)ws_size;

    float* outp = (float*)d_out;                       // out [B,S,HID], f32
    float* attn = outp + (size_t)BB * SS * HIDN;       // attn [B,H,S,S], f32

    char* ws = (char*)d_ws;
    size_t off = 0;
    auto alloc = [&](size_t bytes) { char* p = ws + off; off += (bytes + 255) & ~(size_t)255; return p; };
    const size_t wbytes = (size_t)HIDN * HIDN * sizeof(bf16);
    const size_t tbytes = (size_t)BB * SS * HIDN * sizeof(bf16);
    bf16* WmatT = (bf16*)alloc(4 * wbytes);            // WqT|WkT|WvT|WoT
    bf16* qbf = (bf16*)alloc(tbytes);                  // bf16 inputs (dead after proj)
    bf16* kbf = (bf16*)alloc(tbytes);
    bf16* vbf = (bf16*)alloc(tbytes);
    bf16* qqb = (bf16*)alloc(tbytes);
    bf16* kkb = (bf16*)alloc(tbytes);
    bf16* vvb = (bf16*)alloc(tbytes);
    float* mrowb = (float*)alloc((size_t)BB * NH * SS * sizeof(float));
    float* lrowb = (float*)alloc((size_t)BB * NH * SS * sizeof(float));
    bf16* vvTb = qbf;                                  // alias: qbf dead after q-proj
    bf16* ctxb = kbf;                                  // alias: kbf dead after k-proj
    bf16* WqT = WmatT, *WkT = WmatT + HIDN * HIDN, *WvT = WmatT + 2 * (size_t)HIDN * HIDN,
        *WoT = WmatT + 3 * (size_t)HIDN * HIDN;

    dim3 blk(256);
    cvt_kernel<<<dim3(1024, 3), blk, 0, stream>>>(q, k, v, qbf, kbf, vbf);
    wconv_kernel<<<dim3(16, 16, 4), blk, 0, stream>>>(Wq, Wk, Wv, Wo, WmatT);

    const float scale = 0.08838834764831845f;  // 1/sqrt(128)
    gemm_bt_kernel<bf16><<<dim3(64, 8), blk, 0, stream>>>(qbf, WqT, qqb, scale);
    gemm_bt_kernel<bf16><<<dim3(64, 8), blk, 0, stream>>>(kbf, WkT, kkb, 1.0f);
    gemm_bt_kernel<bf16><<<dim3(64, 8), blk, 0, stream>>>(vbf, WvT, vvb, 1.0f);

    vt_kernel<<<dim3(SS / 64, BB * NH), blk, 0, stream>>>(vvb, vvTb);

    attn_stats_kernel<<<dim3(16, 32), blk, 0, stream>>>(qqb, kkb, mask, mrowb, lrowb);
    attn_pv_kernel<<<dim3(16, 32), blk, 0, stream>>>(qqb, kkb, vvTb, mask, mrowb, lrowb, attn, ctxb);

    gemm_bt_kernel<float><<<dim3(64, 8), blk, 0, stream>>>(ctxb, WoT, outp, 1.0f);
}

// Round 4
// 403.852 us; speedup vs baseline: 1.4097x; 1.0018x over previous
//
#include <hip/hip_runtime.h>
#include <hip/hip_bf16.h>

#define HIDN 1024
#define NH   8
#define DH   128
#define BB   4
#define SS   2048

typedef __bf16 bf16;
typedef bf16 bf16x4 __attribute__((ext_vector_type(4)));
typedef bf16 bf16x8 __attribute__((ext_vector_type(8)));
typedef float f32x4 __attribute__((ext_vector_type(4)));

static __device__ inline f32x4 mfma16(bf16x8 a, bf16x8 b, f32x4 c) {
    return __builtin_amdgcn_mfma_f32_16x16x32_bf16(a, b, c, 0, 0, 0);
}

// async global->LDS, 16B per lane. LDS dest is wave-uniform base + lane*16.
static __device__ inline void gload_lds16(const void* g, void* l) {
    __builtin_amdgcn_global_load_lds(
        (const __attribute__((address_space(1))) unsigned int*)g,
        (__attribute__((address_space(3))) unsigned int*)l, 16, 0, 0);
}

// ---------------- q,k,v f32 -> bf16 (vectorized) -------------------------------
__global__ void cvt_kernel(const float* __restrict__ q, const float* __restrict__ k,
                           const float* __restrict__ v,
                           bf16* __restrict__ qo, bf16* __restrict__ ko, bf16* __restrict__ vo) {
    const float* src = blockIdx.y == 0 ? q : blockIdx.y == 1 ? k : v;
    bf16* dst = blockIdx.y == 0 ? qo : blockIdx.y == 1 ? ko : vo;
    const size_t n = (size_t)BB * SS * HIDN;
    for (size_t i = ((size_t)blockIdx.x * blockDim.x + threadIdx.x) * 8; i < n;
         i += (size_t)gridDim.x * blockDim.x * 8) {
        float4 a = *(const float4*)&src[i];
        float4 b = *(const float4*)&src[i + 4];
        bf16x8 o = {(bf16)a.x, (bf16)a.y, (bf16)a.z, (bf16)a.w,
                    (bf16)b.x, (bf16)b.y, (bf16)b.z, (bf16)b.w};
        *(bf16x8*)&dst[i] = o;
    }
}

// ---------------- weight convert + transpose: W[k][n] f32 -> WT[n][k] bf16 -----
__global__ void wconv_kernel(const float* __restrict__ W0, const float* __restrict__ W1,
                             const float* __restrict__ W2, const float* __restrict__ W3,
                             bf16* __restrict__ O) {
    const float* W = blockIdx.z == 0 ? W0 : blockIdx.z == 1 ? W1 : blockIdx.z == 2 ? W2 : W3;
    bf16* WT = O + (size_t)blockIdx.z * HIDN * HIDN;
    int nb = blockIdx.x * 64;
    int kb = blockIdx.y * 64;
    int t = threadIdx.x;
    __shared__ bf16 tile[64][72];
    {
        int r = t >> 2, cp = (t & 3) * 16;
        #pragma unroll
        for (int j = 0; j < 16; j += 4) {
            float4 val = *(const float4*)&W[(size_t)(kb + r) * HIDN + nb + cp + j];
            tile[r][cp + j + 0] = (bf16)val.x;
            tile[r][cp + j + 1] = (bf16)val.y;
            tile[r][cp + j + 2] = (bf16)val.z;
            tile[r][cp + j + 3] = (bf16)val.w;
        }
    }
    __syncthreads();
    {
        int n = t >> 2, kp = (t & 3) * 16;
        bf16 o[16];
        #pragma unroll
        for (int j = 0; j < 16; ++j) o[j] = tile[kp + j][n];
        #pragma unroll
        for (int j = 0; j < 2; ++j)
            *(bf16x8*)&WT[(size_t)(nb + n) * HIDN + kb + kp + j * 8] = *(bf16x8*)&o[j * 8];
    }
}

// ---------------- GEMM: C[M][1024] = A[M][1024] @ Bt[1024][1024]^T -------------
// Double-buffered global_load_lds (counted vmcnt(8)) + XOR-swizzled LDS.
// OUTMODE: 0 = bf16 row-major, 1 = f32 row-major, 2 = bf16 transposed vvT[B*H][D][S]
template <int OUTMODE>
__global__ __launch_bounds__(256, 2)
void gemm_bt_kernel(const bf16* __restrict__ A, const bf16* __restrict__ Bt,
                    void* __restrict__ Cp, float alpha) {
    __shared__ __align__(16) char smem[65536];   // 2 x (Asm 16KB + Bsm 16KB)
    int orig = blockIdx.x + blockIdx.y * gridDim.x;  // 512 wgs
    int virt = (orig & 7) * 64 + (orig >> 3);        // XCD-contiguous bands
    int bm = (virt & 63) * 128;
    int bn = (virt >> 6) * 128;
    int t = threadIdx.x;
    int wave = t >> 6, lane = t & 63;
    int wr = wave >> 1, wc = wave & 1;
    int lr = lane & 15, lg = lane >> 4;
    int so = wave * 1024 + lane * 16;
    f32x4 acc[4][4] = {};

    auto stage = [&](int k0, char* buf) {
        #pragma unroll
        for (int i = 0; i < 4; ++i) {
            int o = i * 4096 + so;
            int r = o >> 7, cb = o & 127;
            int cbs = cb ^ ((r & 7) << 4);           // inverse-swizzled source
            gload_lds16(&A[(size_t)(bm + r) * HIDN + k0 + (cbs >> 1)], buf + i * 4096 + wave * 1024);
            gload_lds16(&Bt[(size_t)(bn + r) * HIDN + k0 + (cbs >> 1)], buf + 16384 + i * 4096 + wave * 1024);
        }
    };
    stage(0, smem);
    for (int kt = 0; kt < 16; ++kt) {
        const char* cur = smem + (kt & 1) * 32768;
        char* nxt = smem + ((kt & 1) ^ 1) * 32768;
        if (kt < 15) {
            stage((kt + 1) * 64, nxt);
            asm volatile("s_waitcnt vmcnt(8)" ::: "memory");   // wait current tile only
        } else {
            asm volatile("s_waitcnt vmcnt(0)" ::: "memory");
        }
        __syncthreads();
        #pragma unroll
        for (int kd = 0; kd < 2; ++kd) {
            bf16x8 af[4], bfr[4];
            #pragma unroll
            for (int mi = 0; mi < 4; ++mi) {
                int row = wr * 64 + mi * 16 + lr;
                int cb = (kd * 64 + lg * 16) ^ ((row & 7) << 4);
                af[mi] = *(const bf16x8*)(cur + row * 128 + cb);
            }
            #pragma unroll
            for (int ni = 0; ni < 4; ++ni) {
                int row = wc * 64 + ni * 16 + lr;
                int cb = (kd * 64 + lg * 16) ^ ((row & 7) << 4);
                bfr[ni] = *(const bf16x8*)(cur + 16384 + row * 128 + cb);
            }
            #pragma unroll
            for (int mi = 0; mi < 4; ++mi)
                #pragma unroll
                for (int ni = 0; ni < 4; ++ni)
                    acc[mi][ni] = mfma16(af[mi], bfr[ni], acc[mi][ni]);
        }
        __syncthreads();
    }
    if constexpr (OUTMODE == 2) {
        // transpose 128x128 block through LDS, store vvT[(b*8+h)*128+d][s]
        bf16* tile_t = (bf16*)smem;   // [128][136]
        #pragma unroll
        for (int mi = 0; mi < 4; ++mi)
            #pragma unroll
            for (int ni = 0; ni < 4; ++ni) {
                bf16x4 o = {(bf16)acc[mi][ni][0], (bf16)acc[mi][ni][1],
                            (bf16)acc[mi][ni][2], (bf16)acc[mi][ni][3]};
                *(bf16x4*)&tile_t[(wc * 64 + ni * 16 + lr) * 136 + wr * 64 + mi * 16 + lg * 4] = o;
            }
        __syncthreads();
        int d = t >> 1, sh = (t & 1) * 64;
        int b = bm >> 11, h = bn >> 7;
        bf16* vvT = (bf16*)Cp;
        size_t base = ((size_t)(b * NH + h) * DH + d) * SS + (bm & 2047) + sh;
        #pragma unroll
        for (int j = 0; j < 8; ++j)
            *(bf16x8*)&vvT[base + j * 8] = *(const bf16x8*)&tile_t[d * 136 + sh + j * 8];
    } else {
        #pragma unroll
        for (int mi = 0; mi < 4; ++mi)
            #pragma unroll
            for (int ni = 0; ni < 4; ++ni)
                #pragma unroll
                for (int r = 0; r < 4; ++r) {
                    int row = bm + wr * 64 + mi * 16 + lg * 4 + r;
                    int col = bn + wc * 64 + ni * 16 + lr;
                    if constexpr (OUTMODE == 0)
                        ((bf16*)Cp)[(size_t)row * HIDN + col] = (bf16)(acc[mi][ni][r] * alpha);
                    else
                        ((float*)Cp)[(size_t)row * HIDN + col] = acc[mi][ni][r] * alpha;
                }
    }
}

// K-tile staging into swizzled LDS (32KB, 128 rows x 256B)
static __device__ inline void stage_k(const bf16* kbase, int kt, char* Ksm, int wave, int lane) {
    #pragma unroll
    for (int i = 0; i < 8; ++i) {
        int o = i * 4096 + wave * 1024 + lane * 16;
        int r = o >> 8, cb = o & 255;
        int cbs = cb ^ ((r & 7) << 4);
        gload_lds16(&kbase[(size_t)(kt * 128 + r) * HIDN + (cbs >> 1)],
                    Ksm + i * 4096 + wave * 1024);
    }
}

static __device__ inline bf16x8 read_k(const char* Ksm, int row, int cstart_bytes) {
    int cb = cstart_bytes ^ ((row & 7) << 4);
    return *(const bf16x8*)(Ksm + row * 256 + cb);
}

// ---------------- fused attention: stats loop + probs/PV loop ------------------
__global__ __launch_bounds__(256, 2)
void attn_fused_kernel(const bf16* __restrict__ qq, const bf16* __restrict__ kk,
                       const bf16* __restrict__ vvT, const int* __restrict__ mask,
                       float* __restrict__ attn, bf16* __restrict__ ctx) {
    __shared__ __align__(16) char smem[67584];
    char* Ksm0 = smem;                                   // 32KB
    char* Ksm1 = smem + 32768;                           // loop1 dbuf (32KB)
    bf16(*P)[136] = (bf16(*)[136])(smem + 32768);        // loop2 (34816B)
    float* smf = (float*)(smem + 32768);                 // [2][128] between loops
    float* slf = (float*)(smem + 32768 + 1024);

    int orig = blockIdx.x + blockIdx.y * gridDim.x;      // 512
    int virt = (orig & 7) * 64 + (orig >> 3);            // 4 bh-groups per XCD
    int qt = virt & 15, bh = virt >> 4;
    int b = bh >> 3, h = bh & 7;
    int t = threadIdx.x;
    int wave = t >> 6, lane = t & 63;
    int wr = wave >> 1, wc = wave & 1;
    int lr = lane & 15, lg = lane >> 4;

    const bf16* qbase = qq + (size_t)b * SS * HIDN + h * DH;
    const bf16* kbase = kk + (size_t)b * SS * HIDN + h * DH;
    const int* mbase = mask + b * SS;

    // Q fragments (persistent)
    bf16x8 qf[4][4];
    #pragma unroll
    for (int mi = 0; mi < 4; ++mi)
        #pragma unroll
        for (int kd = 0; kd < 4; ++kd)
            qf[mi][kd] = *(const bf16x8*)&qbase[(size_t)(qt * 128 + wr * 64 + mi * 16 + lr) * HIDN + kd * 32 + lg * 8];

    // mask bits for this thread's 4 columns per tile, all 16 tiles
    unsigned long long mkbits = 0;
    #pragma unroll
    for (int kt = 0; kt < 16; ++kt)
        #pragma unroll
        for (int ni = 0; ni < 4; ++ni)
            mkbits |= (unsigned long long)(mbase[kt * 128 + wc * 64 + ni * 16 + lr] != 0)
                      << (kt * 4 + ni);

    // ---- loop 1: online stats, per-thread (no per-tile cross-lane ops) ----
    float m_[16], l_[16];
    #pragma unroll
    for (int s = 0; s < 16; ++s) { m_[s] = -3.4e38f; l_[s] = 0.f; }

    stage_k(kbase, 0, Ksm0, wave, lane);
    for (int kt = 0; kt < 16; ++kt) {
        const char* cur = (kt & 1) ? Ksm1 : Ksm0;
        char* nxt = (kt & 1) ? Ksm0 : Ksm1;
        if (kt < 15) {
            stage_k(kbase, kt + 1, nxt, wave, lane);
            asm volatile("s_waitcnt vmcnt(8)" ::: "memory");
        } else {
            asm volatile("s_waitcnt vmcnt(0)" ::: "memory");
        }
        __syncthreads();
        f32x4 acc[4][4] = {};
        #pragma unroll
        for (int kd = 0; kd < 4; ++kd) {
            bf16x8 kf[4];
            #pragma unroll
            for (int ni = 0; ni < 4; ++ni)
                kf[ni] = read_k(cur, wc * 64 + ni * 16 + lr, kd * 64 + lg * 16);
            #pragma unroll
            for (int mi = 0; mi < 4; ++mi)
                #pragma unroll
                for (int ni = 0; ni < 4; ++ni)
                    acc[mi][ni] = mfma16(qf[mi][kd], kf[ni], acc[mi][ni]);
        }
        #pragma unroll
        for (int mi = 0; mi < 4; ++mi)
            #pragma unroll
            for (int r = 0; r < 4; ++r) {
                int s = mi * 4 + r;
                float v0 = ((mkbits >> (kt * 4 + 0)) & 1) ? -1e9f : acc[mi][0][r];
                float v1 = ((mkbits >> (kt * 4 + 1)) & 1) ? -1e9f : acc[mi][1][r];
                float v2 = ((mkbits >> (kt * 4 + 2)) & 1) ? -1e9f : acc[mi][2][r];
                float v3 = ((mkbits >> (kt * 4 + 3)) & 1) ? -1e9f : acc[mi][3][r];
                float tm = fmaxf(fmaxf(v0, v1), fmaxf(v2, v3));
                float tl = __expf(v0 - tm) + __expf(v1 - tm) + __expf(v2 - tm) + __expf(v3 - tm);
                float mo = m_[s], mn = fmaxf(mo, tm);
                l_[s] = l_[s] * __expf(mo - mn) + tl * __expf(tm - mn);
                m_[s] = mn;
            }
        __syncthreads();
    }

    // prefetch loop2 tile 0 while reducing
    stage_k(kbase, 0, Ksm0, wave, lane);

    // reduce across lr (16-lane butterfly), then across wc via LDS
    #pragma unroll
    for (int o = 1; o < 16; o <<= 1)
        #pragma unroll
        for (int s = 0; s < 16; ++s) {
            float mo = __shfl_xor(m_[s], o);
            float lo = __shfl_xor(l_[s], o);
            float mn = fmaxf(m_[s], mo);
            l_[s] = l_[s] * __expf(m_[s] - mn) + lo * __expf(mo - mn);
            m_[s] = mn;
        }
    if (lr == 0) {
        #pragma unroll
        for (int mi = 0; mi < 4; ++mi)
            #pragma unroll
            for (int r = 0; r < 4; ++r) {
                int row = wr * 64 + mi * 16 + lg * 4 + r;
                smf[wc * 128 + row] = m_[mi * 4 + r];
                slf[wc * 128 + row] = l_[mi * 4 + r];
            }
    }
    __syncthreads();
    float rm[16], rl[16];
    #pragma unroll
    for (int mi = 0; mi < 4; ++mi)
        #pragma unroll
        for (int r = 0; r < 4; ++r) {
            int row = wr * 64 + mi * 16 + lg * 4 + r;
            float m0 = smf[row], m1 = smf[128 + row];
            float l0 = slf[row], l1 = slf[128 + row];
            float mn = fmaxf(m0, m1);
            float l = l0 * __expf(m0 - mn) + l1 * __expf(m1 - mn);
            rm[mi * 4 + r] = mn;
            rl[mi * 4 + r] = 1.0f / l;
        }
    asm volatile("s_waitcnt vmcnt(0)" ::: "memory");
    __syncthreads();   // Ksm0 tile 0 staged & visible; smf reads done before P writes

    // ---- loop 2: probs (attn out + P) and PV ----
    f32x4 cacc[4][4] = {};
    for (int kt = 0; kt < 16; ++kt) {
        f32x4 acc[4][4] = {};
        #pragma unroll
        for (int kd = 0; kd < 4; ++kd) {
            bf16x8 kf[4];
            #pragma unroll
            for (int ni = 0; ni < 4; ++ni)
                kf[ni] = read_k(Ksm0, wc * 64 + ni * 16 + lr, kd * 64 + lg * 16);
            #pragma unroll
            for (int mi = 0; mi < 4; ++mi)
                #pragma unroll
                for (int ni = 0; ni < 4; ++ni)
                    acc[mi][ni] = mfma16(qf[mi][kd], kf[ni], acc[mi][ni]);
        }
        #pragma unroll
        for (int mi = 0; mi < 4; ++mi)
            #pragma unroll
            for (int ni = 0; ni < 4; ++ni)
                #pragma unroll
                for (int r = 0; r < 4; ++r) {
                    float s = ((mkbits >> (kt * 4 + ni)) & 1) ? -1e9f : acc[mi][ni][r];
                    float p = __expf(s - rm[mi * 4 + r]) * rl[mi * 4 + r];
                    int rowl = wr * 64 + mi * 16 + lg * 4 + r;
                    int coll = wc * 64 + ni * 16 + lr;
                    P[rowl][coll] = (bf16)p;
                    __builtin_nontemporal_store(
                        p, &attn[((size_t)bh * SS + qt * 128 + rowl) * SS + kt * 128 + coll]);
                }
        __syncthreads();                       // K reads done, P visible
        if (kt < 15) stage_k(kbase, kt + 1, Ksm0, wave, lane);   // hide under PV
        #pragma unroll
        for (int ks = 0; ks < 4; ++ks) {
            bf16x8 pf[4], vf[4];
            #pragma unroll
            for (int mi = 0; mi < 4; ++mi)
                pf[mi] = *(const bf16x8*)&P[wr * 64 + mi * 16 + lr][ks * 32 + lg * 8];
            #pragma unroll
            for (int ni = 0; ni < 4; ++ni)
                vf[ni] = *(const bf16x8*)&vvT[((size_t)bh * DH + wc * 64 + ni * 16 + lr) * SS + kt * 128 + ks * 32 + lg * 8];
            #pragma unroll
            for (int mi = 0; mi < 4; ++mi)
                #pragma unroll
                for (int ni = 0; ni < 4; ++ni)
                    cacc[mi][ni] = mfma16(pf[mi], vf[ni], cacc[mi][ni]);
        }
        asm volatile("s_waitcnt vmcnt(0)" ::: "memory");
        __syncthreads();                       // P reads done, next K staged
    }
    #pragma unroll
    for (int mi = 0; mi < 4; ++mi)
        #pragma unroll
        for (int ni = 0; ni < 4; ++ni)
            #pragma unroll
            for (int r = 0; r < 4; ++r) {
                int qrow = qt * 128 + wr * 64 + mi * 16 + lg * 4 + r;
                int d = wc * 64 + ni * 16 + lr;
                ctx[((size_t)b * SS + qrow) * HIDN + h * DH + d] = (bf16)cacc[mi][ni][r];
            }
}

extern "C" void kernel_launch(void* const* d_in, const int* in_sizes, int n_in,
                              void* d_out, int out_size, void* d_ws, size_t ws_size,
                              hipStream_t stream) {
    const float* q = (const float*)d_in[0];
    const float* k = (const float*)d_in[1];
    const float* v = (const float*)d_in[2];
    const int* mask = (const int*)d_in[3];
    const float* Wq = (const float*)d_in[4];
    const float* Wk = (const float*)d_in[5];
    const float* Wv = (const float*)d_in[6];
    const float* Wo = (const float*)d_in[7];
    (void)in_sizes; (void)n_in; (void)out_size; (void)ws_size;

    float* outp = (float*)d_out;                       // out [B,S,HID], f32
    float* attn = outp + (size_t)BB * SS * HIDN;       // attn [B,H,S,S], f32

    char* ws = (char*)d_ws;
    size_t off = 0;
    auto alloc = [&](size_t bytes) { char* p = ws + off; off += (bytes + 255) & ~(size_t)255; return p; };
    const size_t wbytes = (size_t)HIDN * HIDN * sizeof(bf16);
    const size_t tbytes = (size_t)BB * SS * HIDN * sizeof(bf16);
    bf16* WmatT = (bf16*)alloc(4 * wbytes);            // WqT|WkT|WvT|WoT
    bf16* qbf = (bf16*)alloc(tbytes);
    bf16* kbf = (bf16*)alloc(tbytes);
    bf16* vbf = (bf16*)alloc(tbytes);
    bf16* qqb = (bf16*)alloc(tbytes);
    bf16* kkb = (bf16*)alloc(tbytes);
    bf16* vvTb = (bf16*)alloc(tbytes);
    bf16* ctxb = qbf;                                  // alias: qbf dead after q-proj
    bf16* WqT = WmatT, *WkT = WmatT + (size_t)HIDN * HIDN,
        *WvT = WmatT + 2 * (size_t)HIDN * HIDN, *WoT = WmatT + 3 * (size_t)HIDN * HIDN;

    dim3 blk(256);
    cvt_kernel<<<dim3(1024, 3), blk, 0, stream>>>(q, k, v, qbf, kbf, vbf);
    wconv_kernel<<<dim3(16, 16, 4), blk, 0, stream>>>(Wq, Wk, Wv, Wo, WmatT);

    const float scale = 0.08838834764831845f;  // 1/sqrt(128)
    gemm_bt_kernel<0><<<dim3(64, 8), blk, 0, stream>>>(qbf, WqT, qqb, scale);
    gemm_bt_kernel<0><<<dim3(64, 8), blk, 0, stream>>>(kbf, WkT, kkb, 1.0f);
    gemm_bt_kernel<2><<<dim3(64, 8), blk, 0, stream>>>(vbf, WvT, vvTb, 1.0f);  // writes vvT directly

    attn_fused_kernel<<<dim3(16, 32), blk, 0, stream>>>(qqb, kkb, vvTb, mask, attn, ctxb);

    gemm_bt_kernel<1><<<dim3(64, 8), blk, 0, stream>>>(ctxb, WoT, outp, 1.0f);
}